// Round 1
// baseline (120.254 us; speedup 1.0000x reference)
//
#include <hip/hip_runtime.h>
#include <math.h>

static constexpr int HH = 2048;
static constexpr int WW = 2048;
static constexpr int NPIX = HH * WW;

// Pass A: fw = sum of 5 binary masks (exact small ints), stored as uchar.
__global__ __launch_bounds__(256) void k_fw(const float* __restrict__ t,
                                            unsigned char* __restrict__ fw) {
    int base = (blockIdx.x * 256 + threadIdx.x) * 4;
    float4 a = *(const float4*)(t + 0 * NPIX + base);
    float4 b = *(const float4*)(t + 1 * NPIX + base);
    float4 c = *(const float4*)(t + 2 * NPIX + base);
    float4 d = *(const float4*)(t + 3 * NPIX + base);
    float4 e = *(const float4*)(t + 4 * NPIX + base);
    uchar4 u;
    u.x = (unsigned char)(a.x + b.x + c.x + d.x + e.x);
    u.y = (unsigned char)(a.y + b.y + c.y + d.y + e.y);
    u.z = (unsigned char)(a.z + b.z + c.z + d.z + e.z);
    u.w = (unsigned char)(a.w + b.w + c.w + d.w + e.w);
    *(uchar4*)(fw + base) = u;
}

// Pass B: per-pixel min squared distance to a differing 'combined' pixel in
// the 9x9 (edge-clamped) neighborhood; w = (fw + 1/sqrt(msq))^2.
// Block-level min/max partials written per block (no atomics).
__global__ __launch_bounds__(256) void k_w(const unsigned char* __restrict__ fw,
                                           float* __restrict__ wout,
                                           float* __restrict__ bmin,
                                           float* __restrict__ bmax) {
    const int x = blockIdx.x * 64 + threadIdx.x;   // blockDim = (64,4)
    const int y = blockIdx.y * 4 + threadIdx.y;
    const int idx = y * WW + x;
    const int fwv = fw[idx];
    const int c = fwv > 0 ? 1 : 0;
    int msq = 1 << 28;

    const bool interior = (x >= 4) & (x < WW - 4) & (y >= 4) & (y < HH - 4);
    if (interior) {
#pragma unroll
        for (int dy = -4; dy <= 4; ++dy) {
#pragma unroll
            for (int dx = -4; dx <= 4; ++dx) {
                if (dx == 0 && dy == 0) continue;
                int n = fw[idx + dy * WW + dx] > 0 ? 1 : 0;
                const int d2 = dy * dy + dx * dx;
                msq = (n != c && d2 < msq) ? d2 : msq;
            }
        }
    } else {
#pragma unroll
        for (int dy = -4; dy <= 4; ++dy) {
            int yy = min(max(y + dy, 0), HH - 1);
#pragma unroll
            for (int dx = -4; dx <= 4; ++dx) {
                if (dx == 0 && dy == 0) continue;
                int xx = min(max(x + dx, 0), WW - 1);
                int n = fw[yy * WW + xx] > 0 ? 1 : 0;
                const int d2 = dy * dy + dx * dx;
                msq = (n != c && d2 < msq) ? d2 : msq;
            }
        }
    }

    float contour = (msq < (1 << 28)) ? 1.0f / sqrtf((float)msq) : 0.0f;
    float wv = (float)fwv + contour;
    wv *= wv;
    wout[idx] = wv;

    // block reduction: 4 waves of 64
    float mn = wv, mx = wv;
#pragma unroll
    for (int off = 32; off > 0; off >>= 1) {
        mn = fminf(mn, __shfl_down(mn, off));
        mx = fmaxf(mx, __shfl_down(mx, off));
    }
    __shared__ float smn[4], smx[4];
    const int tid = threadIdx.y * 64 + threadIdx.x;
    if ((tid & 63) == 0) { smn[tid >> 6] = mn; smx[tid >> 6] = mx; }
    __syncthreads();
    if (tid == 0) {
        mn = fminf(fminf(smn[0], smn[1]), fminf(smn[2], smn[3]));
        mx = fmaxf(fmaxf(smx[0], smx[1]), fmaxf(smx[2], smx[3]));
        const int bid = blockIdx.y * gridDim.x + blockIdx.x;
        bmin[bid] = mn;
        bmax[bid] = mx;
    }
}

// Pass C: single block reduces all per-block partials.
__global__ __launch_bounds__(256) void k_red(const float* __restrict__ bmin,
                                             const float* __restrict__ bmax,
                                             float* __restrict__ mm, int n) {
    float mn = INFINITY, mx = -INFINITY;
    for (int i = threadIdx.x; i < n; i += 256) {
        mn = fminf(mn, bmin[i]);
        mx = fmaxf(mx, bmax[i]);
    }
#pragma unroll
    for (int off = 32; off > 0; off >>= 1) {
        mn = fminf(mn, __shfl_down(mn, off));
        mx = fmaxf(mx, __shfl_down(mx, off));
    }
    __shared__ float smn[4], smx[4];
    if ((threadIdx.x & 63) == 0) { smn[threadIdx.x >> 6] = mn; smx[threadIdx.x >> 6] = mx; }
    __syncthreads();
    if (threadIdx.x == 0) {
        mn = fminf(fminf(smn[0], smn[1]), fminf(smn[2], smn[3]));
        mx = fmaxf(fmaxf(smx[0], smx[1]), fmaxf(smx[2], smx[3]));
        mm[0] = mn;
        mm[1] = mx;
    }
}

// Pass D: in-place normalize + mask by combined.
__global__ __launch_bounds__(256) void k_norm(float* __restrict__ w,
                                              const unsigned char* __restrict__ fw,
                                              const float* __restrict__ mm) {
    const float mn = mm[0];
    const float inv = 1.0f / (mm[1] - mn + 1e-10f);
    const int base = (blockIdx.x * 256 + threadIdx.x) * 4;
    float4 v = *(const float4*)(w + base);
    uchar4 f = *(const uchar4*)(fw + base);
    v.x = f.x ? (v.x - mn) * inv : 0.0f;
    v.y = f.y ? (v.y - mn) * inv : 0.0f;
    v.z = f.z ? (v.z - mn) * inv : 0.0f;
    v.w = f.w ? (v.w - mn) * inv : 0.0f;
    *(float4*)(w + base) = v;
}

extern "C" void kernel_launch(void* const* d_in, const int* in_sizes, int n_in,
                              void* d_out, int out_size, void* d_ws, size_t ws_size,
                              hipStream_t stream) {
    const float* target = (const float*)d_in[0];
    float* out = (float*)d_out;

    unsigned char* fw = (unsigned char*)d_ws;
    const int nblk = (WW / 64) * (HH / 4);           // 16384
    float* bmin = (float*)((char*)d_ws + NPIX);      // 4 MB offset
    float* bmax = bmin + nblk;
    float* mm = bmax + nblk;

    k_fw<<<NPIX / 4 / 256, 256, 0, stream>>>(target, fw);

    dim3 blk(64, 4);
    dim3 grd(WW / 64, HH / 4);
    k_w<<<grd, blk, 0, stream>>>(fw, out, bmin, bmax);

    k_red<<<1, 256, 0, stream>>>(bmin, bmax, mm, nblk);

    k_norm<<<NPIX / 4 / 256, 256, 0, stream>>>(out, fw, mm);
}

// Round 2
// 72.969 us; speedup vs baseline: 1.6480x; 1.6480x over previous
//
#include <hip/hip_runtime.h>
#include <math.h>

static constexpr int HH = 2048;
static constexpr int WW = 2048;
static constexpr int NPIX = HH * WW;
static constexpr int WPR = WW / 64;   // 32 packed words per row

// Rank of squared distance among the 14 distinct d2 values in the 9x9
// neighborhood (ascending). 0 = "no differing neighbor".
__host__ __device__ constexpr int rank_of(int d2) {
    switch (d2) {
        case 1:  return 1;  case 2:  return 2;  case 4:  return 3;
        case 5:  return 4;  case 8:  return 5;  case 9:  return 6;
        case 10: return 7;  case 13: return 8;  case 16: return 9;
        case 17: return 10; case 18: return 11; case 20: return 12;
        case 25: return 13; case 32: return 14;
    }
    return 0;
}

// Pass A: fw byte map (sum of 5 binary masks) + bit-packed combined mask.
// Thread handles 8 consecutive pixels. Also zeroes the observed-code mask.
__global__ __launch_bounds__(256) void k_pack(const float* __restrict__ t,
                                              unsigned char* __restrict__ fw,
                                              unsigned char* __restrict__ pk,
                                              unsigned long long* __restrict__ obs) {
    const int tid = blockIdx.x * 256 + threadIdx.x;
    if (tid == 0) { obs[0] = 0ull; obs[1] = 0ull; }
    const int base = tid * 8;
    unsigned long long fwq = 0;
    unsigned int bits = 0;
#pragma unroll
    for (int h = 0; h < 2; ++h) {
        const int o = base + 4 * h;
        float4 a = *(const float4*)(t + 0 * NPIX + o);
        float4 b = *(const float4*)(t + 1 * NPIX + o);
        float4 c = *(const float4*)(t + 2 * NPIX + o);
        float4 d = *(const float4*)(t + 3 * NPIX + o);
        float4 e = *(const float4*)(t + 4 * NPIX + o);
        const float s0 = a.x + b.x + c.x + d.x + e.x;
        const float s1 = a.y + b.y + c.y + d.y + e.y;
        const float s2 = a.z + b.z + c.z + d.z + e.z;
        const float s3 = a.w + b.w + c.w + d.w + e.w;
        const int j = 4 * h;
        fwq |= ((unsigned long long)(int)s0) << (8 * j);
        fwq |= ((unsigned long long)(int)s1) << (8 * (j + 1));
        fwq |= ((unsigned long long)(int)s2) << (8 * (j + 2));
        fwq |= ((unsigned long long)(int)s3) << (8 * (j + 3));
        bits |= (s0 > 0.f ? 1u : 0u) << j;
        bits |= (s1 > 0.f ? 1u : 0u) << (j + 1);
        bits |= (s2 > 0.f ? 1u : 0u) << (j + 2);
        bits |= (s3 > 0.f ? 1u : 0u) << (j + 3);
    }
    *(unsigned long long*)(fw + base) = fwq;
    pk[tid] = (unsigned char)bits;
}

// Pass B: bit-parallel min-squared-distance classification.
// One thread per 64-pixel word. Emits 1 code byte per pixel:
// code = (fw << 4) | rank, and ORs observed codes into obs[2].
__global__ __launch_bounds__(256) void k_dist(const unsigned long long* __restrict__ pk,
                                              const unsigned long long* __restrict__ fw8,
                                              unsigned long long* __restrict__ code8,
                                              unsigned long long* __restrict__ obs) {
    const int t = blockIdx.x * 256 + threadIdx.x;   // word index, 65536 total
    const int y = t >> 5;
    const int wx = t & (WPR - 1);

    unsigned long long acc[15];
#pragma unroll
    for (int i = 0; i < 15; ++i) acc[i] = 0ull;

    const unsigned long long C = pk[y * WPR + wx];

#pragma unroll
    for (int dy = -4; dy <= 4; ++dy) {
        const int yy = min(max(y + dy, 0), HH - 1);
        const unsigned long long M = pk[yy * WPR + wx];
        const unsigned long long L =
            (wx > 0) ? pk[yy * WPR + wx - 1] : ((M & 1ull) ? ~0ull : 0ull);
        const unsigned long long R =
            (wx < WPR - 1) ? pk[yy * WPR + wx + 1] : ((M >> 63) ? ~0ull : 0ull);
#pragma unroll
        for (int dx = -4; dx <= 4; ++dx) {
            if (dx == 0 && dy == 0) continue;
            unsigned long long S;
            if (dx > 0)      S = (M >> dx) | (R << (64 - dx));
            else if (dx < 0) S = (M << (-dx)) | (L >> (64 + dx));
            else             S = M;
            acc[rank_of(dy * dy + dx * dx)] |= S ^ C;
        }
    }

    // Resolve ascending distance into 4-bit class per pixel (4 bitplanes).
    unsigned long long found = 0, p0 = 0, p1 = 0, p2 = 0, p3 = 0;
#pragma unroll
    for (int r = 1; r <= 14; ++r) {
        const unsigned long long nw = acc[r] & ~found;
        found |= acc[r];
        if (r & 1) p0 |= nw;
        if (r & 2) p1 |= nw;
        if (r & 4) p2 |= nw;
        if (r & 8) p3 |= nw;
    }

    // Epilogue: emit code bytes, track observed codes.
    unsigned long long lo = 0, hi = 0;
#pragma unroll
    for (int j = 0; j < 8; ++j) {
        const unsigned long long f = fw8[t * 8 + j];
        unsigned long long cq = 0;
#pragma unroll
        for (int b = 0; b < 8; ++b) {
            const int x = j * 8 + b;
            const unsigned int cls = (unsigned int)((p0 >> x) & 1)
                                   | ((unsigned int)((p1 >> x) & 1) << 1)
                                   | ((unsigned int)((p2 >> x) & 1) << 2)
                                   | ((unsigned int)((p3 >> x) & 1) << 3);
            const unsigned int fv = (unsigned int)((f >> (8 * b)) & 0xff);
            const unsigned int code = (fv << 4) | cls;
            cq |= ((unsigned long long)code) << (8 * b);
            const unsigned long long bit = 1ull << (code & 63);
            lo |= (code & 64) ? 0ull : bit;
            hi |= (code & 64) ? bit : 0ull;
        }
        code8[t * 8 + j] = cq;
    }

    // Wave-level OR reduce, one atomicOr pair per wave (idempotent -> deterministic).
#pragma unroll
    for (int s = 32; s > 0; s >>= 1) {
        lo |= __shfl_xor(lo, s);
        hi |= __shfl_xor(hi, s);
    }
    if ((threadIdx.x & 63) == 0) {
        atomicOr(&obs[0], lo);
        atomicOr(&obs[1], hi);
    }
}

// Pass C: min/max over the <=96 observed code values; emit normalized
// output value per code.
__global__ void k_mm(const unsigned long long* __restrict__ obs,
                     float* __restrict__ normtab) {
    if (threadIdx.x != 0 || blockIdx.x != 0) return;
    const int D2S[15] = {0, 1, 2, 4, 5, 8, 9, 10, 13, 16, 17, 18, 20, 25, 32};
    const unsigned long long lo = obs[0], hi = obs[1];
    float wv[96];
    float mn = INFINITY, mx = -INFINITY;
    for (int code = 0; code < 96; ++code) {
        const int fv = code >> 4;
        const int r = code & 15;
        const float contour = (r >= 1 && r <= 14) ? 1.f / sqrtf((float)D2S[r]) : 0.f;
        float v = (float)fv + contour;
        v *= v;
        wv[code] = v;
        const bool present = (code < 64) ? ((lo >> code) & 1) : ((hi >> (code - 64)) & 1);
        if (present) { mn = fminf(mn, v); mx = fmaxf(mx, v); }
    }
    const float inv = 1.f / (mx - mn + 1e-10f);
    for (int code = 0; code < 96; ++code) {
        const int fv = code >> 4;
        normtab[code] = (fv > 0) ? (wv[code] - mn) * inv : 0.f;
    }
}

// Pass D: out[pixel] = normtab[code[pixel]] via 96-entry LDS table.
__global__ __launch_bounds__(256) void k_out(const unsigned long long* __restrict__ code8,
                                             const float* __restrict__ normtab,
                                             float* __restrict__ out) {
    __shared__ float tab[96];
    if (threadIdx.x < 96) tab[threadIdx.x] = normtab[threadIdx.x];
    __syncthreads();
    const int t = blockIdx.x * 256 + threadIdx.x;
    const unsigned long long cq = code8[t];
    float4 v0, v1;
    v0.x = tab[(cq >> 0) & 0xff];
    v0.y = tab[(cq >> 8) & 0xff];
    v0.z = tab[(cq >> 16) & 0xff];
    v0.w = tab[(cq >> 24) & 0xff];
    v1.x = tab[(cq >> 32) & 0xff];
    v1.y = tab[(cq >> 40) & 0xff];
    v1.z = tab[(cq >> 48) & 0xff];
    v1.w = tab[(cq >> 56) & 0xff];
    *(float4*)(out + t * 8) = v0;
    *(float4*)(out + t * 8 + 4) = v1;
}

extern "C" void kernel_launch(void* const* d_in, const int* in_sizes, int n_in,
                              void* d_out, int out_size, void* d_ws, size_t ws_size,
                              hipStream_t stream) {
    const float* target = (const float*)d_in[0];
    float* out = (float*)d_out;

    // ws layout (all 8B-aligned): fw | packed | code | obs | normtab
    unsigned char* fw = (unsigned char*)d_ws;                         // NPIX bytes
    unsigned char* pk = fw + NPIX;                                    // NPIX/8 bytes
    unsigned char* code = pk + NPIX / 8;                              // NPIX bytes
    unsigned long long* obs = (unsigned long long*)(code + NPIX);     // 16 bytes
    float* normtab = (float*)(obs + 2);                               // 96 floats

    k_pack<<<NPIX / 8 / 256, 256, 0, stream>>>(target, fw, pk, obs);

    k_dist<<<(NPIX / 64) / 256, 256, 0, stream>>>(
        (const unsigned long long*)pk, (const unsigned long long*)fw,
        (unsigned long long*)code, obs);

    k_mm<<<1, 64, 0, stream>>>(obs, normtab);

    k_out<<<NPIX / 8 / 256, 256, 0, stream>>>(
        (const unsigned long long*)code, normtab, out);
}

// Round 3
// 57.859 us; speedup vs baseline: 2.0784x; 1.2611x over previous
//
#include <hip/hip_runtime.h>
#include <math.h>

static constexpr int HH = 2048;
static constexpr int WW = 2048;
static constexpr int NPIX = HH * WW;
static constexpr int WPR = WW / 64;   // 32 packed words per row

// Rank of squared distance among the 14 distinct d2 values in the 9x9
// neighborhood (ascending). 0 = "no differing neighbor".
__host__ __device__ constexpr int rank_of(int d2) {
    switch (d2) {
        case 1:  return 1;  case 2:  return 2;  case 4:  return 3;
        case 5:  return 4;  case 8:  return 5;  case 9:  return 6;
        case 10: return 7;  case 13: return 8;  case 16: return 9;
        case 17: return 10; case 18: return 11; case 20: return 12;
        case 25: return 13; case 32: return 14;
    }
    return 0;
}

__device__ const int D2S[16] = {0, 1, 2, 4, 5, 8, 9, 10, 13, 16, 17, 18, 20, 25, 32, 0};

// Pass A: fw byte map (sum of 5 binary masks) + bit-packed combined mask.
// Thread handles 8 consecutive pixels. Also zeroes the observed-code mask.
__global__ __launch_bounds__(256) void k_pack(const float* __restrict__ t,
                                              unsigned char* __restrict__ fw,
                                              unsigned char* __restrict__ pk,
                                              unsigned long long* __restrict__ obs) {
    const int tid = blockIdx.x * 256 + threadIdx.x;
    if (tid == 0) { obs[0] = 0ull; obs[1] = 0ull; }
    const int base = tid * 8;
    unsigned long long fwq = 0;
    unsigned int bits = 0;
#pragma unroll
    for (int h = 0; h < 2; ++h) {
        const int o = base + 4 * h;
        float4 a = *(const float4*)(t + 0 * NPIX + o);
        float4 b = *(const float4*)(t + 1 * NPIX + o);
        float4 c = *(const float4*)(t + 2 * NPIX + o);
        float4 d = *(const float4*)(t + 3 * NPIX + o);
        float4 e = *(const float4*)(t + 4 * NPIX + o);
        const float s0 = a.x + b.x + c.x + d.x + e.x;
        const float s1 = a.y + b.y + c.y + d.y + e.y;
        const float s2 = a.z + b.z + c.z + d.z + e.z;
        const float s3 = a.w + b.w + c.w + d.w + e.w;
        const int j = 4 * h;
        fwq |= ((unsigned long long)(int)s0) << (8 * j);
        fwq |= ((unsigned long long)(int)s1) << (8 * (j + 1));
        fwq |= ((unsigned long long)(int)s2) << (8 * (j + 2));
        fwq |= ((unsigned long long)(int)s3) << (8 * (j + 3));
        bits |= (s0 > 0.f ? 1u : 0u) << j;
        bits |= (s1 > 0.f ? 1u : 0u) << (j + 1);
        bits |= (s2 > 0.f ? 1u : 0u) << (j + 2);
        bits |= (s3 > 0.f ? 1u : 0u) << (j + 3);
    }
    *(unsigned long long*)(fw + base) = fwq;
    pk[tid] = (unsigned char)bits;
}

// Pass B: bit-parallel min-squared-distance classification.
// One thread per 64-pixel word. Emits 1 code byte per pixel:
// code = (fw << 4) | rank, and ORs observed codes into obs[2].
__global__ __launch_bounds__(256) void k_dist(const unsigned long long* __restrict__ pk,
                                              const unsigned long long* __restrict__ fw8,
                                              unsigned long long* __restrict__ code8,
                                              unsigned long long* __restrict__ obs) {
    const int t = blockIdx.x * 256 + threadIdx.x;   // word index, 65536 total
    const int y = t >> 5;
    const int wx = t & (WPR - 1);

    unsigned long long acc[15];
#pragma unroll
    for (int i = 0; i < 15; ++i) acc[i] = 0ull;

    const unsigned long long C = pk[y * WPR + wx];

#pragma unroll
    for (int dy = -4; dy <= 4; ++dy) {
        const int yy = min(max(y + dy, 0), HH - 1);
        const unsigned long long M = pk[yy * WPR + wx];
        const unsigned long long L =
            (wx > 0) ? pk[yy * WPR + wx - 1] : ((M & 1ull) ? ~0ull : 0ull);
        const unsigned long long R =
            (wx < WPR - 1) ? pk[yy * WPR + wx + 1] : ((M >> 63) ? ~0ull : 0ull);
#pragma unroll
        for (int dx = -4; dx <= 4; ++dx) {
            if (dx == 0 && dy == 0) continue;
            unsigned long long S;
            if (dx > 0)      S = (M >> dx) | (R << (64 - dx));
            else if (dx < 0) S = (M << (-dx)) | (L >> (64 + dx));
            else             S = M;
            acc[rank_of(dy * dy + dx * dx)] |= S ^ C;
        }
    }

    // Resolve ascending distance into 4-bit class per pixel (4 bitplanes).
    unsigned long long found = 0, p0 = 0, p1 = 0, p2 = 0, p3 = 0;
#pragma unroll
    for (int r = 1; r <= 14; ++r) {
        const unsigned long long nw = acc[r] & ~found;
        found |= acc[r];
        if (r & 1) p0 |= nw;
        if (r & 2) p1 |= nw;
        if (r & 4) p2 |= nw;
        if (r & 8) p3 |= nw;
    }

    // Epilogue: emit code bytes, track observed codes.
    unsigned long long lo = 0, hi = 0;
#pragma unroll
    for (int j = 0; j < 8; ++j) {
        const unsigned long long f = fw8[t * 8 + j];
        unsigned long long cq = 0;
#pragma unroll
        for (int b = 0; b < 8; ++b) {
            const int x = j * 8 + b;
            const unsigned int cls = (unsigned int)((p0 >> x) & 1)
                                   | ((unsigned int)((p1 >> x) & 1) << 1)
                                   | ((unsigned int)((p2 >> x) & 1) << 2)
                                   | ((unsigned int)((p3 >> x) & 1) << 3);
            const unsigned int fv = (unsigned int)((f >> (8 * b)) & 0xff);
            const unsigned int code = (fv << 4) | cls;
            cq |= ((unsigned long long)code) << (8 * b);
            const unsigned long long bit = 1ull << (code & 63);
            lo |= (code & 64) ? 0ull : bit;
            hi |= (code & 64) ? bit : 0ull;
        }
        code8[t * 8 + j] = cq;
    }

    // Wave-level OR reduce, one atomicOr pair per wave (idempotent -> deterministic).
#pragma unroll
    for (int s = 32; s > 0; s >>= 1) {
        lo |= __shfl_xor(lo, s);
        hi |= __shfl_xor(hi, s);
    }
    if ((threadIdx.x & 63) == 0) {
        atomicOr(&obs[0], lo);
        atomicOr(&obs[1], hi);
    }
}

// Pass C: per-block table build (96 parallel lanes, no scratch arrays) +
// out[pixel] = tab[code[pixel]] via 96-entry LDS table.
__global__ __launch_bounds__(256) void k_out(const unsigned long long* __restrict__ code8,
                                             const unsigned long long* __restrict__ obs,
                                             float* __restrict__ out) {
    __shared__ float tab[96];
    __shared__ float smn[4], smx[4];

    const int tid = threadIdx.x;
    const unsigned long long lo = obs[0], hi = obs[1];

    float v = 0.f;
    bool present = false;
    if (tid < 96) {
        const int r = tid & 15;
        const float contour = (r >= 1 && r <= 14) ? 1.f / sqrtf((float)D2S[r]) : 0.f;
        const float t0 = (float)(tid >> 4) + contour;
        v = t0 * t0;
        present = (tid < 64) ? ((lo >> tid) & 1) : ((hi >> (tid - 64)) & 1);
    }
    float mnv = present ? v : INFINITY;
    float mxv = present ? v : -INFINITY;
#pragma unroll
    for (int s = 32; s > 0; s >>= 1) {
        mnv = fminf(mnv, __shfl_xor(mnv, s));
        mxv = fmaxf(mxv, __shfl_xor(mxv, s));
    }
    if ((tid & 63) == 0) { smn[tid >> 6] = mnv; smx[tid >> 6] = mxv; }
    __syncthreads();
    const float mn = fminf(fminf(smn[0], smn[1]), fminf(smn[2], smn[3]));
    const float mx = fmaxf(fmaxf(smx[0], smx[1]), fmaxf(smx[2], smx[3]));
    const float inv = 1.f / (mx - mn + 1e-10f);
    if (tid < 96) tab[tid] = (tid >= 16) ? (v - mn) * inv : 0.f;  // fv==0 -> masked to 0
    __syncthreads();

    const int t = blockIdx.x * 256 + tid;
    const unsigned long long cq = code8[t];
    float4 v0, v1;
    v0.x = tab[(cq >> 0) & 0xff];
    v0.y = tab[(cq >> 8) & 0xff];
    v0.z = tab[(cq >> 16) & 0xff];
    v0.w = tab[(cq >> 24) & 0xff];
    v1.x = tab[(cq >> 32) & 0xff];
    v1.y = tab[(cq >> 40) & 0xff];
    v1.z = tab[(cq >> 48) & 0xff];
    v1.w = tab[(cq >> 56) & 0xff];
    *(float4*)(out + t * 8) = v0;
    *(float4*)(out + t * 8 + 4) = v1;
}

extern "C" void kernel_launch(void* const* d_in, const int* in_sizes, int n_in,
                              void* d_out, int out_size, void* d_ws, size_t ws_size,
                              hipStream_t stream) {
    const float* target = (const float*)d_in[0];
    float* out = (float*)d_out;

    // ws layout (all 8B-aligned): fw | packed | code | obs
    unsigned char* fw = (unsigned char*)d_ws;                         // NPIX bytes
    unsigned char* pk = fw + NPIX;                                    // NPIX/8 bytes
    unsigned char* code = pk + NPIX / 8;                              // NPIX bytes
    unsigned long long* obs = (unsigned long long*)(code + NPIX);     // 16 bytes

    k_pack<<<NPIX / 8 / 256, 256, 0, stream>>>(target, fw, pk, obs);

    k_dist<<<(NPIX / 64) / 256, 256, 0, stream>>>(
        (const unsigned long long*)pk, (const unsigned long long*)fw,
        (unsigned long long*)code, obs);

    k_out<<<NPIX / 8 / 256, 256, 0, stream>>>(
        (const unsigned long long*)code, obs, out);
}

// Round 5
// 56.129 us; speedup vs baseline: 2.1424x; 1.0308x over previous
//
#include <hip/hip_runtime.h>
#include <math.h>
#include <utility>

static constexpr int HH = 2048;
static constexpr int WW = 2048;
static constexpr int NPIX = HH * WW;
static constexpr int WPR = WW / 64;   // 32 packed u64 words per row

// Compile-time-forced loop unrolling: every index/shift below becomes a
// literal constant, so acc[] stays in registers (rule #20).
template <typename F, int... Is>
__device__ __forceinline__ void sf_impl(F&& f, std::integer_sequence<int, Is...>) {
    (f(std::integral_constant<int, Is>{}), ...);
}
template <int N, typename F>
__device__ __forceinline__ void static_for(F&& f) {
    sf_impl(f, std::make_integer_sequence<int, N>{});
}

// Rank of squared distance among the 14 distinct d2 values in the 9x9
// neighborhood (ascending). 0 = "no differing neighbor".
__host__ __device__ constexpr int rank_of(int d2) {
    switch (d2) {
        case 1:  return 1;  case 2:  return 2;  case 4:  return 3;
        case 5:  return 4;  case 8:  return 5;  case 9:  return 6;
        case 10: return 7;  case 13: return 8;  case 16: return 9;
        case 17: return 10; case 18: return 11; case 20: return 12;
        case 25: return 13; case 32: return 14;
    }
    return 0;
}

__device__ const int D2S[16] = {0, 1, 2, 4, 5, 8, 9, 10, 13, 16, 17, 18, 20, 25, 32, 0};

// Spread the 8 bits of b into the 8 bytes of a u64 (byte i = (b>>i)&1).
__device__ __forceinline__ unsigned long long spread8(unsigned int b) {
    unsigned long long t = (unsigned long long)b * 0x0101010101010101ull;
    t &= 0x8040201008040201ull;                       // byte i keeps bit i
    return ((t + 0x7f7f7f7f7f7f7f7full) >> 7) & 0x0101010101010101ull;
}

// Pass A: fw byte map (sum of 5 binary masks) + bit-packed combined mask.
__global__ __launch_bounds__(256) void k_pack(const float* __restrict__ t,
                                              unsigned char* __restrict__ fw,
                                              unsigned char* __restrict__ pk,
                                              unsigned long long* __restrict__ obs) {
    const int tid = blockIdx.x * 256 + threadIdx.x;
    if (tid == 0) { obs[0] = 0ull; obs[1] = 0ull; }
    const int base = tid * 8;
    unsigned long long fwq = 0;
    unsigned int bits = 0;
#pragma unroll
    for (int h = 0; h < 2; ++h) {
        const int o = base + 4 * h;
        float4 a = *(const float4*)(t + 0 * NPIX + o);
        float4 b = *(const float4*)(t + 1 * NPIX + o);
        float4 c = *(const float4*)(t + 2 * NPIX + o);
        float4 d = *(const float4*)(t + 3 * NPIX + o);
        float4 e = *(const float4*)(t + 4 * NPIX + o);
        const float s0 = a.x + b.x + c.x + d.x + e.x;
        const float s1 = a.y + b.y + c.y + d.y + e.y;
        const float s2 = a.z + b.z + c.z + d.z + e.z;
        const float s3 = a.w + b.w + c.w + d.w + e.w;
        const int j = 4 * h;
        fwq |= ((unsigned long long)(int)s0) << (8 * j);
        fwq |= ((unsigned long long)(int)s1) << (8 * (j + 1));
        fwq |= ((unsigned long long)(int)s2) << (8 * (j + 2));
        fwq |= ((unsigned long long)(int)s3) << (8 * (j + 3));
        bits |= (s0 > 0.f ? 1u : 0u) << j;
        bits |= (s1 > 0.f ? 1u : 0u) << (j + 1);
        bits |= (s2 > 0.f ? 1u : 0u) << (j + 2);
        bits |= (s3 > 0.f ? 1u : 0u) << (j + 3);
    }
    *(unsigned long long*)(fw + base) = fwq;
    pk[tid] = (unsigned char)bits;
}

// Pass B: bit-parallel min-squared-distance classification, fully
// compile-time-unrolled (acc[] indices all constexpr -> registers).
__global__ __launch_bounds__(256) void k_dist(const unsigned long long* __restrict__ pk,
                                              const unsigned long long* __restrict__ fw8,
                                              unsigned long long* __restrict__ code8,
                                              unsigned long long* __restrict__ obs) {
    const int t = blockIdx.x * 256 + threadIdx.x;   // word index, 65536 total
    const int y = t >> 5;
    const int wx = t & (WPR - 1);

    unsigned long long acc[15];
    static_for<15>([&](auto I) { acc[I.value] = 0ull; });

    const unsigned long long C = pk[y * WPR + wx];

    static_for<9>([&](auto DY) {
        constexpr int dy = DY.value - 4;
        const int yy = min(max(y + dy, 0), HH - 1);
        const unsigned long long M = pk[yy * WPR + wx];
        const unsigned long long L =
            (wx > 0) ? pk[yy * WPR + wx - 1] : ((M & 1ull) ? ~0ull : 0ull);
        const unsigned long long R =
            (wx < WPR - 1) ? pk[yy * WPR + wx + 1] : ((M >> 63) ? ~0ull : 0ull);
        static_for<9>([&](auto DX) {
            constexpr int dx = DX.value - 4;
            if constexpr (!(dx == 0 && dy == 0)) {
                constexpr int rk = rank_of(dy * dy + dx * dx);
                unsigned long long S;
                if constexpr (dx > 0)      S = (M >> dx) | (R << (64 - dx));
                else if constexpr (dx < 0) S = (M << (-dx)) | (L >> (64 + dx));
                else                       S = M;
                acc[rk] |= S ^ C;
            }
        });
    });

    // Resolve ascending distance into 4 bitplanes (first-found = min d2).
    unsigned long long found = 0, p0 = 0, p1 = 0, p2 = 0, p3 = 0;
    static_for<14>([&](auto RI) {
        constexpr int r = RI.value + 1;
        const unsigned long long nw = acc[r] & ~found;
        found |= acc[r];
        if constexpr (r & 1) p0 |= nw;
        if constexpr (r & 2) p1 |= nw;
        if constexpr (r & 4) p2 |= nw;
        if constexpr (r & 8) p3 |= nw;
    });

    // Epilogue: emit code bytes (code = fv<<4 | class) via bit-spread;
    // track observed codes.
    unsigned long long lo = 0, hi = 0;
    static_for<8>([&](auto J) {
        constexpr int j = J.value;
        const unsigned long long f = fw8[t * 8 + j];
        const unsigned int c0 = (unsigned int)((p0 >> (8 * j)) & 0xff);
        const unsigned int c1 = (unsigned int)((p1 >> (8 * j)) & 0xff);
        const unsigned int c2 = (unsigned int)((p2 >> (8 * j)) & 0xff);
        const unsigned int c3 = (unsigned int)((p3 >> (8 * j)) & 0xff);
        const unsigned long long cls = spread8(c0) | (spread8(c1) << 1)
                                     | (spread8(c2) << 2) | (spread8(c3) << 3);
        const unsigned long long cq = (f << 4) | cls;   // fv<=5 so no nibble overflow
        code8[t * 8 + j] = cq;
        static_for<8>([&](auto B) {
            constexpr int b = B.value;
            const unsigned int code = (unsigned int)((cq >> (8 * b)) & 0xff);
            const unsigned long long bit = 1ull << (code & 63);
            const bool ishi = (code & 64) != 0;
            lo |= ishi ? 0ull : bit;
            hi |= ishi ? bit : 0ull;
        });
    });

    // Wave OR-reduce, one atomicOr pair per wave (idempotent -> deterministic).
#pragma unroll
    for (int s = 32; s > 0; s >>= 1) {
        lo |= __shfl_xor(lo, s);
        hi |= __shfl_xor(hi, s);
    }
    if ((threadIdx.x & 63) == 0) {
        atomicOr(&obs[0], lo);
        atomicOr(&obs[1], hi);
    }
}

// Pass C: per-block table build (96 parallel lanes) + LDS-table lookup.
__global__ __launch_bounds__(256) void k_out(const unsigned long long* __restrict__ code8,
                                             const unsigned long long* __restrict__ obs,
                                             float* __restrict__ out) {
    __shared__ float tab[96];
    __shared__ float smn[4], smx[4];

    const int tid = threadIdx.x;
    const unsigned long long lo = obs[0], hi = obs[1];

    float v = 0.f;
    bool present = false;
    if (tid < 96) {
        const int r = tid & 15;
        const float contour = (r >= 1 && r <= 14) ? 1.f / sqrtf((float)D2S[r]) : 0.f;
        const float t0 = (float)(tid >> 4) + contour;
        v = t0 * t0;
        present = (tid < 64) ? ((lo >> tid) & 1) : ((hi >> (tid - 64)) & 1);
    }
    float mnv = present ? v : INFINITY;
    float mxv = present ? v : -INFINITY;
#pragma unroll
    for (int s = 32; s > 0; s >>= 1) {
        mnv = fminf(mnv, __shfl_xor(mnv, s));
        mxv = fmaxf(mxv, __shfl_xor(mxv, s));
    }
    if ((tid & 63) == 0) { smn[tid >> 6] = mnv; smx[tid >> 6] = mxv; }
    __syncthreads();
    const float mn = fminf(fminf(smn[0], smn[1]), fminf(smn[2], smn[3]));
    const float mx = fmaxf(fmaxf(smx[0], smx[1]), fmaxf(smx[2], smx[3]));
    const float inv = 1.f / (mx - mn + 1e-10f);
    if (tid < 96) tab[tid] = (tid >= 16) ? (v - mn) * inv : 0.f;  // fv==0 -> 0
    __syncthreads();

    const int t = blockIdx.x * 256 + tid;
    const unsigned long long cq = code8[t];
    float4 v0, v1;
    v0.x = tab[(cq >> 0) & 0xff];
    v0.y = tab[(cq >> 8) & 0xff];
    v0.z = tab[(cq >> 16) & 0xff];
    v0.w = tab[(cq >> 24) & 0xff];
    v1.x = tab[(cq >> 32) & 0xff];
    v1.y = tab[(cq >> 40) & 0xff];
    v1.z = tab[(cq >> 48) & 0xff];
    v1.w = tab[(cq >> 56) & 0xff];
    *(float4*)(out + t * 8) = v0;
    *(float4*)(out + t * 8 + 4) = v1;
}

extern "C" void kernel_launch(void* const* d_in, const int* in_sizes, int n_in,
                              void* d_out, int out_size, void* d_ws, size_t ws_size,
                              hipStream_t stream) {
    const float* target = (const float*)d_in[0];
    float* out = (float*)d_out;

    // ws layout (8B-aligned): fw | packed | code | obs
    unsigned char* fw = (unsigned char*)d_ws;                         // NPIX bytes
    unsigned char* pk = fw + NPIX;                                    // NPIX/8 bytes
    unsigned char* code = pk + NPIX / 8;                              // NPIX bytes
    unsigned long long* obs = (unsigned long long*)(code + NPIX);     // 16 bytes

    k_pack<<<NPIX / 8 / 256, 256, 0, stream>>>(target, fw, pk, obs);

    k_dist<<<(NPIX / 64) / 256, 256, 0, stream>>>(
        (const unsigned long long*)pk, (const unsigned long long*)fw,
        (unsigned long long*)code, obs);

    k_out<<<NPIX / 8 / 256, 256, 0, stream>>>(
        (const unsigned long long*)code, obs, out);
}